// Round 1
// 318.051 us; speedup vs baseline: 1.0020x; 1.0020x over previous
//
#include <hip/hip_runtime.h>
#include <float.h>

#define BB 256
#define DD 256
#define KK 1024
#define EE 16
#define DECAY 0.999f
#define GAIN  0.001f
#define EPS   1e-6f

// output offsets in floats (tuple order: cw_embed, one_hot, new_codebook, new_ema)
#define OH_OFF   ((size_t)BB * DD * EE)                    // 1048576
#define CB_OFF   (OH_OFF + (size_t)BB * DD * KK)           // 68157440
#define EMA_OFF  (CB_OFF + (size_t)DD * KK * EE)           // 72351744

typedef float f32x4 __attribute__((ext_vector_type(4)));

__device__ __forceinline__ float dot16(const float4& a0, const float4& a1,
                                       const float4& a2, const float4& a3,
                                       const float4& b0, const float4& b1,
                                       const float4& b2, const float4& b3) {
  float s = a0.x * b0.x;
  s = fmaf(a0.y, b0.y, s); s = fmaf(a0.z, b0.z, s); s = fmaf(a0.w, b0.w, s);
  s = fmaf(a1.x, b1.x, s); s = fmaf(a1.y, b1.y, s); s = fmaf(a1.z, b1.z, s); s = fmaf(a1.w, b1.w, s);
  s = fmaf(a2.x, b2.x, s); s = fmaf(a2.y, b2.y, s); s = fmaf(a2.z, b2.z, s); s = fmaf(a2.w, b2.w, s);
  s = fmaf(a3.x, b3.x, s); s = fmaf(a3.y, b3.y, s); s = fmaf(a3.z, b3.z, s); s = fmaf(a3.w, b3.w, s);
  return s;
}

// monotonic ordered-uint of an f32; key = ord<<32 | k. atomicMin -> smallest
// dist, lowest k on exact ties (identical to strict-< ascending-k scan).
__device__ __forceinline__ unsigned long long packkey(float dist, int k) {
  unsigned u = __float_as_uint(dist);
  unsigned m = ((int)u < 0) ? 0xFFFFFFFFu : 0x80000000u;
  return ((unsigned long long)(u ^ m) << 32) | (unsigned long long)(unsigned)k;
}

__device__ __forceinline__ void ntst4(float4* p, float4 v) {
  f32x4 t = { v.x, v.y, v.z, v.w };
  __builtin_nontemporal_store(t, (f32x4*)p);
}

// One block per d. 1024 threads = 16 waves (4/SIMD -> 2x latency hiding vs 8).
// Wave w scans k in [64w, 64w+64); each lane holds x for 4 b's (b = lane+64j).
// Argmin merged via packed-u64 LDS atomicMin (no pbest/pidxs, no merge phase).
// one_hot zero-fill: 16 stores/thread in prologue (overlaps staging), 48 in loop.
// LDS ~143 KB -> 1 block/CU, 16 waves/CU.
__global__ __launch_bounds__(1024) void vqvae_fused(
    const float* __restrict__ cw_q,      // (B, D*E)
    const float* __restrict__ codebook,  // (D, K, E)
    const float* __restrict__ ema,       // (D, K)
    float* __restrict__ out)
{
  __shared__ float4 cb4s[KK * EE / 4];            // 64 KB codebook row d
  __shared__ float4 upd4s[KK * EE / 4];           // 64 KB update accumulator
  __shared__ float  c2s[KK];                      // 4 KB |c|^2
  __shared__ float  esh[KK];                      // 4 KB old ema (prefetched)
  __shared__ float  cnts[KK];                     // 4 KB
  __shared__ unsigned long long amin[BB];         // 2 KB packed argmin
  __shared__ int    ish[BB];                      // 1 KB

  const int t = threadIdx.x;
  const int d = blockIdx.x;
  const int w = t >> 6;
  const int l = t & 63;
  const float4 z4 = make_float4(0.f, 0.f, 0.f, 0.f);

  // ---- P0: init LDS, prefetch ema, stage codebook, load x fragments ----
  cnts[t] = 0.f;
  if (t < BB) amin[t] = ~0ULL;
  esh[t] = ema[(size_t)d * KK + t];
  #pragma unroll
  for (int i = 0; i < 4; ++i) upd4s[i * 1024 + t] = z4;

  const float4* src4 = (const float4*)codebook + (size_t)d * (KK * EE / 4);
  #pragma unroll
  for (int i = 0; i < 4; ++i) {
    int i4 = i * 1024 + t;
    float4 v = src4[i4];
    cb4s[i4] = v;
    float sq = v.x * v.x;
    sq = fmaf(v.y, v.y, sq);
    sq = fmaf(v.z, v.z, sq);
    sq = fmaf(v.w, v.w, sq);
    sq += __shfl_xor(sq, 1);
    sq += __shfl_xor(sq, 2);
    if ((t & 3) == 0) c2s[i4 >> 2] = sq;
  }

  float4 xv[4][4];
  float  x2[4];
  #pragma unroll
  for (int j = 0; j < 4; ++j) {
    const int b = l + 64 * j;
    const float4* xr = (const float4*)cw_q + (size_t)b * (DD * EE / 4) + d * 4;
    xv[j][0] = xr[0]; xv[j][1] = xr[1]; xv[j][2] = xr[2]; xv[j][3] = xr[3];
  }

  // wave w owns one_hot rows b in [16w, 16w+16) for column block d
  float* ohp = out + OH_OFF;
  float4* zb = (float4*)(ohp + (size_t)(w << 4) * (DD * KK) + (size_t)d * KK) + l;

  // prologue zero-fill: rows 0..3 of this wave's 16 (store pipe busy during staging)
  #pragma unroll
  for (int f = 0; f < 16; ++f)
    ntst4(&zb[(size_t)(f >> 2) * (DD * KK / 4) + (f & 3) * 64], z4);

  #pragma unroll
  for (int j = 0; j < 4; ++j)
    x2[j] = dot16(xv[j][0], xv[j][1], xv[j][2], xv[j][3],
                  xv[j][0], xv[j][1], xv[j][2], xv[j][3]);

  __syncthreads();

  // ---- P1: main loop, 64 k's per wave ----
  float best[4] = {FLT_MAX, FLT_MAX, FLT_MAX, FLT_MAX};
  int   bi[4]   = {0, 0, 0, 0};
  const int kbase = w << 6;

  auto body = [&](int s) {
    const int k = kbase + s;
    const float4* p = cb4s + (k << 2);     // wave-uniform -> LDS broadcast
    float4 c0 = p[0], c1 = p[1], c2v = p[2], c3 = p[3];
    const float c2k = c2s[k];
    #pragma unroll
    for (int j = 0; j < 4; ++j) {
      float dj = dot16(c0, c1, c2v, c3, xv[j][0], xv[j][1], xv[j][2], xv[j][3]);
      float dist = fmaf(-2.f, dj, x2[j] + c2k);
      if (dist < best[j]) { best[j] = dist; bi[j] = k; }   // strict <: lowest k wins
    }
  };

  #pragma unroll 1
  for (int s = 0; s < 48; ++s) {
    body(s);
    // interleaved zero-fill of remaining rows 4..15 (f = 16+s)
    ntst4(&zb[(size_t)(4 + (s >> 2)) * (DD * KK / 4) + (s & 3) * 64], z4);
  }
  #pragma unroll 1
  for (int s = 48; s < 64; ++s) body(s);

  // flush per-thread argmin into packed atomicMin (replaces wave-merge phase)
  #pragma unroll
  for (int j = 0; j < 4; ++j)
    atomicMin(&amin[l + 64 * j], packkey(best[j], bi[j]));

  __syncthreads();   // drains zero-stores (vmcnt) + amin atomics

  // ---- P2: epilogue per b + prefetch scatter operands (addresses static) ----
  const int e = t & 15;
  const int g = t >> 4;                    // 64 groups handle 4 b's each
  float xpre[4];
  #pragma unroll
  for (int i = 0; i < 4; ++i)
    xpre[i] = cw_q[(size_t)(g * 4 + i) * (DD * EE) + (size_t)d * EE + e];

  if (t < BB) {
    const int b = t;
    unsigned long long key = amin[b];
    const int bidx = (int)(unsigned)(key & 0xFFFFFFFFull);

    float4* ce = (float4*)out + (size_t)b * (DD * EE / 4) + d * 4;
    const float4* cwp = cb4s + (bidx << 2);
    ntst4(&ce[0], cwp[0]); ntst4(&ce[1], cwp[1]);
    ntst4(&ce[2], cwp[2]); ntst4(&ce[3], cwp[3]);

    __builtin_nontemporal_store(
        1.0f, &ohp[(size_t)b * (DD * KK) + (size_t)d * KK + bidx]);

    ish[b] = bidx;
    atomicAdd(&cnts[bidx], 1.0f);
  }
  __syncthreads();

  // ---- P3+P4 merged: update scatter (e-split banks) + new_ema ----
  {
    float* upd = (float*)upd4s;
    #pragma unroll
    for (int i = 0; i < 4; ++i) {
      int k = ish[g * 4 + i];
      atomicAdd(&upd[k * EE + e], xpre[i]);
    }
    float* oe = out + EMA_OFF + (size_t)d * KK;
    __builtin_nontemporal_store(DECAY * esh[t] + GAIN * cnts[t], &oe[t]);
  }
  __syncthreads();

  // ---- P5: new_codebook ----
  {
    float4* ocb = (float4*)(out + CB_OFF) + (size_t)d * (KK * EE / 4);
    #pragma unroll
    for (int i = 0; i < 4; ++i) {
      int i4 = i * 1024 + t;
      int k  = i4 >> 2;
      float4 c = cb4s[i4];
      float4 u = upd4s[i4];
      float inv = GAIN / (esh[k] + EPS);
      float4 r;
      r.x = DECAY * c.x + u.x * inv;
      r.y = DECAY * c.y + u.y * inv;
      r.z = DECAY * c.z + u.z * inv;
      r.w = DECAY * c.w + u.w * inv;
      ntst4(&ocb[i4], r);
    }
  }
}

extern "C" void kernel_launch(void* const* d_in, const int* in_sizes, int n_in,
                              void* d_out, int out_size, void* d_ws, size_t ws_size,
                              hipStream_t stream) {
  const float* cw_q     = (const float*)d_in[0];
  const float* codebook = (const float*)d_in[1];
  const float* ema      = (const float*)d_in[2];
  float* out = (float*)d_out;
  (void)in_sizes; (void)n_in; (void)out_size; (void)d_ws; (void)ws_size;

  vqvae_fused<<<dim3(DD), dim3(1024), 0, stream>>>(cw_q, codebook, ema, out);
}